// Round 6
// baseline (276.808 us; speedup 1.0000x reference)
//
#include <hip/hip_runtime.h>
#include <math.h>

#define B_ 4
#define S_ 2048
#define E_ 1024
#define H_ 16
#define D_ 64
#define BH_ (B_ * H_)

// 1/sqrt(64) * log2(e): folded into Wq/bq so QK^T scores are in exp2 domain
#define SCALE_LOG2E 0.18033688011112042f

typedef short short8 __attribute__((ext_vector_type(8)));   // 8 bf16 (4 VGPR)
typedef float f32x4 __attribute__((ext_vector_type(4)));    // MFMA accumulator
typedef float f32x16 __attribute__((ext_vector_type(16)));  // 32x32 accumulator

static __device__ __forceinline__ unsigned short f2bf(float f) {
    unsigned int u = __float_as_uint(f);
    unsigned int r = (u + 0x7fffu + ((u >> 16) & 1u)) >> 16;
    return (unsigned short)r;
}

// pack two fp32 -> two bf16 (truncation) in one v_perm_b32; low short = lo
static __device__ __forceinline__ unsigned int pack_bf16_trunc(float hi, float lo) {
    return __builtin_amdgcn_perm(__float_as_uint(hi), __float_as_uint(lo), 0x07060302u);
}

// async global->LDS DMA, 16B per lane. LDS dest = base + lane*16 (HW rule).
static __device__ __forceinline__ void gl_lds16(const unsigned short* g, unsigned short* l) {
    __builtin_amdgcn_global_load_lds(
        (const __attribute__((address_space(1))) unsigned int*)g,
        (__attribute__((address_space(3))) unsigned int*)l, 16, 0, 0);
}

// ---------------------------------------------------------------------------
// Slice layouts (attn inputs, R2): every attn MFMA fragment read touches a
// 32-row x 32B = 1024B subset; stored contiguously in global:
//   Qg/Kg: [bh][S/32][kc=4][ 32 rows ][ 2 k-half ][ 8 ]   (512 shorts/slice)
//   Vg   : [bh][S/64][sv=8][ 32 drows ][ 2 k-half ][ 8 ]
// GEMM LDS tiles (R6): 128 rows x 32 shorts (BK=32), 64B rows. Chunk swizzle
// swz(r) = (r&3)^((r>>2)&3): per-16-lane read group covers 8 (parity,chunk)
// bank-sets x2 lanes = 2-way = free. [R1/R2 lesson: derive swizzle for the
// exact lane geometry; old c^(r&7) is 4-way at 64B rows.]
// ---------------------------------------------------------------------------

// ---------------------------------------------------------------------------
// Prep: x fp32 -> bf16, 8 elems/thread
// ---------------------------------------------------------------------------
__global__ __launch_bounds__(256) void xcvt_kernel(
    const float* __restrict__ x, unsigned short* __restrict__ Xb)
{
    size_t i = ((size_t)blockIdx.x * 256 + threadIdx.x) * 8;
    float4 a = *(const float4*)&x[i];
    float4 b = *(const float4*)&x[i + 4];
    ushort4 u0, u1;
    u0.x = f2bf(a.x); u0.y = f2bf(a.y); u0.z = f2bf(a.z); u0.w = f2bf(a.w);
    u1.x = f2bf(b.x); u1.y = f2bf(b.y); u1.z = f2bf(b.z); u1.w = f2bf(b.w);
    *(ushort4*)&Xb[i]     = u0;
    *(ushort4*)&Xb[i + 4] = u1;
}

// ---------------------------------------------------------------------------
// Prep: fused Wq/Wk/Wv transpose fp32 [E][D] -> bf16 [D][E] per head.
// z: 0..15 Wq (scaled), 16..31 Wk, 32..47 Wv.
// ---------------------------------------------------------------------------
__global__ __launch_bounds__(256) void wtrans_qkv_kernel(
    const float* __restrict__ Wq, const float* __restrict__ Wk,
    const float* __restrict__ Wv, unsigned short* __restrict__ Wt)
{
    __shared__ float t[32][33];
    const int tx = threadIdx.x & 31, ty = threadIdx.x >> 5;
    const int r0 = blockIdx.x * 32, c0 = blockIdx.y * 32;
    const int z = blockIdx.z, mtx = z >> 4, h = z & 15;
    const float* s = (mtx == 0 ? Wq : (mtx == 1 ? Wk : Wv)) + (size_t)h * E_ * D_;
    const float scale = (mtx == 0) ? SCALE_LOG2E : 1.0f;
    unsigned short* d = Wt + (size_t)mtx * E_ * E_ + (size_t)h * D_ * E_;
#pragma unroll
    for (int i = 0; i < 4; ++i)
        t[ty + i * 8][tx] = s[(size_t)(r0 + ty + i * 8) * D_ + c0 + tx];
    __syncthreads();
#pragma unroll
    for (int i = 0; i < 4; ++i)
        d[(size_t)(c0 + ty + i * 8) * E_ + r0 + tx] = f2bf(t[tx][ty + i * 8] * scale);
}

// ---------------------------------------------------------------------------
// Prep: transpose fp32 [R][C] -> bf16 [C][R] (Wo)
// ---------------------------------------------------------------------------
__global__ __launch_bounds__(256) void wtrans_kernel(
    const float* __restrict__ src, unsigned short* __restrict__ dst, int R, int C)
{
    __shared__ float t[32][33];
    const int tx = threadIdx.x & 31, ty = threadIdx.x >> 5;
    const int r0 = blockIdx.x * 32, c0 = blockIdx.y * 32;
#pragma unroll
    for (int i = 0; i < 4; ++i)
        t[ty + i * 8][tx] = src[(size_t)(r0 + ty + i * 8) * C + c0 + tx];
    __syncthreads();
#pragma unroll
    for (int i = 0; i < 4; ++i)
        dst[(size_t)(c0 + ty + i * 8) * R + r0 + tx] = f2bf(t[tx][ty + i * 8]);
}

// ---------------------------------------------------------------------------
// Kernel 1: fused QKV projection GEMM, C[8192 x 3072] = Xb * W^T (+bias).
// R6: BK=32, 32KB LDS -> 4 blocks/CU resident (was 2); barrier drains now
// covered by cross-block TLP. [R5 PMC: MfmaUtil 22 / VALU 12 / occ 20 =
// latency-bound at 2 blocks/CU.]
// ---------------------------------------------------------------------------
__global__ __launch_bounds__(256, 4) void qkv_gemm_kernel(
    const unsigned short* __restrict__ Xb, const unsigned short* __restrict__ Wt,
    const float* __restrict__ bq, const float* __restrict__ bk,
    const float* __restrict__ bv,
    unsigned short* __restrict__ Qh, unsigned short* __restrict__ Kh,
    unsigned short* __restrict__ Vth)
{
    __shared__ unsigned short As[2][128 * 32];
    __shared__ unsigned short Bs[2][128 * 32];
    const int tid = threadIdx.x;
    const int lane = tid & 63, wid = tid >> 6;
    const int quad = lane >> 4, lc = lane & 15;
    const int wm = wid >> 1, wn = wid & 1;
    const int m0 = blockIdx.y * 128, n0 = blockIdx.x * 128;
    const int srow = lane >> 2;                         // staged row within 16
    const int sch  = (((lane & 3) ^ ((lane >> 2) & 3) ^ ((lane >> 4) & 3))) * 8;
    const int swzr = (lc & 3) ^ ((lc >> 2) & 3);        // read-side swizzle

    f32x4 acc[4][4];
#pragma unroll
    for (int mt = 0; mt < 4; ++mt)
#pragma unroll
        for (int nt = 0; nt < 4; ++nt)
            acc[mt][nt] = (f32x4){0.f, 0.f, 0.f, 0.f};

    // prologue: stage k0=0 into buffer 0 (2 issues per matrix per wave)
#pragma unroll
    for (int i = 0; i < 2; ++i) {
        int rw = wid * 32 + i * 16;
        gl_lds16(&Xb[(size_t)(m0 + rw + srow) * E_ + sch], &As[0][rw * 32]);
        gl_lds16(&Wt[(size_t)(n0 + rw + srow) * E_ + sch], &Bs[0][rw * 32]);
    }
    __syncthreads();

    for (int k0 = 0; k0 < E_; k0 += 32) {
        const int cur = (k0 >> 5) & 1;
        if (k0 + 32 < E_) {
#pragma unroll
            for (int i = 0; i < 2; ++i) {
                int rw = wid * 32 + i * 16;
                gl_lds16(&Xb[(size_t)(m0 + rw + srow) * E_ + k0 + 32 + sch], &As[cur ^ 1][rw * 32]);
                gl_lds16(&Wt[(size_t)(n0 + rw + srow) * E_ + k0 + 32 + sch], &Bs[cur ^ 1][rw * 32]);
            }
        }
        short8 a[4], bfr[4];
#pragma unroll
        for (int mt = 0; mt < 4; ++mt)
            a[mt] = *(const short8*)&As[cur][(wm * 64 + mt * 16 + lc) * 32 +
                                            ((quad ^ swzr) << 3)];
#pragma unroll
        for (int nt = 0; nt < 4; ++nt)
            bfr[nt] = *(const short8*)&Bs[cur][(wn * 64 + nt * 16 + lc) * 32 +
                                              ((quad ^ swzr) << 3)];
#pragma unroll
        for (int mt = 0; mt < 4; ++mt)
#pragma unroll
            for (int nt = 0; nt < 4; ++nt)
                acc[mt][nt] = __builtin_amdgcn_mfma_f32_16x16x32_bf16(
                    a[mt], bfr[nt], acc[mt][nt], 0, 0, 0);
        __syncthreads();
    }

    const int nb = n0 + wn * 64;
    const int mtx = nb >> 10;               // 0=Q 1=K 2=V
    const int h = (nb >> 6) & 15;
    const int sg0 = m0 + wm * 64;           // tile rows all in one batch
    const int bb_ = sg0 >> 11;
    const int bhv = bb_ * H_ + h;
    if (mtx < 2) {
        const float bsc = (mtx == 0) ? SCALE_LOG2E : 1.0f;
        const float* bias = (mtx == 0 ? bq : bk) + h * D_;
        unsigned short* Out = (mtx == 0) ? Qh : Kh;
        const size_t obase = (size_t)bhv * (S_ / 32) * 2048;   // 4 slices * 512
#pragma unroll
        for (int nt = 0; nt < 4; ++nt) {
            int d = nt * 16 + lc;
            int hi_ = (lc >> 3) & 1, j = lc & 7;
            float bb = bias[d] * bsc;
#pragma unroll
            for (int mt = 0; mt < 4; ++mt)
#pragma unroll
                for (int r = 0; r < 4; ++r) {
                    int ss = (sg0 + mt * 16 + quad * 4 + r) & (S_ - 1);
                    // Qg/Kg: [bh][s>>5][kc=nt][(s&31)*2 + hi][j]
                    Out[obase + ((size_t)(ss >> 5) * 4 + nt) * 512 +
                        ((ss & 31) * 2 + hi_) * 8 + j] = f2bf(acc[mt][nt][r] + bb);
                }
        }
    } else {
        const float* bias = bv + h * D_;
        const size_t obase = (size_t)bhv * (S_ / 64) * 4096;   // 8 slices * 512
        const int t64 = (sg0 & (S_ - 1)) >> 6;
        const int hi_ = quad >> 1, j0 = (quad & 1) * 4;
#pragma unroll
        for (int nt = 0; nt < 4; ++nt) {
            int d = nt * 16 + lc;
            int dsub = d >> 5, l31d = d & 31;
            float bb = bias[d];
#pragma unroll
            for (int mt = 0; mt < 4; ++mt) {
                // Vg slice sv = mt*2 + dsub ; within: [l31d*2 + hi][j0..j0+3]
                ushort4 u;
                u.x = f2bf(acc[mt][nt][0] + bb);
                u.y = f2bf(acc[mt][nt][1] + bb);
                u.z = f2bf(acc[mt][nt][2] + bb);
                u.w = f2bf(acc[mt][nt][3] + bb);
                *(ushort4*)&Vth[obase + ((size_t)t64 * 8 + mt * 2 + dsub) * 512 +
                                (l31d * 2 + hi_) * 8 + j0] = u;
            }
        }
    }
}

// ---------------------------------------------------------------------------
// Kernel 2: flash attention, no-max streaming softmax, 32x32 swapped-QK route.
// R5 structure (kept): cross-tile software pipeline at 32-key-half
// granularity; 3-buffer ring; 512-thread blocks, 2 blocks/CU, 16 waves/CU.
// ---------------------------------------------------------------------------
__global__ __launch_bounds__(512, 4) void attn_kernel(
    const unsigned short* __restrict__ Qh, const unsigned short* __restrict__ Kh,
    const unsigned short* __restrict__ Vth, unsigned short* __restrict__ Ch)
{
    __shared__ unsigned short ks[3][8 * 512];   // [buf][slice kb*4+kc][512]
    __shared__ unsigned short vt[3][8 * 512];   // [buf][slice sv][512]
    const int tid = threadIdx.x;
    const int lane = tid & 63, wid = tid >> 6;   // wid 0..7
    const int l31 = lane & 31, hi = lane >> 5;
    const int bh = blockIdx.x, b = bh >> 4, h = bh & 15;
    const int q0 = blockIdx.y * 256;
    const size_t gbase = (size_t)bh * (S_ / 32) * 2048;  // per-bh slice base
    const int rdoff = (l31 * 2 + hi) * 8;   // within-slice fragment offset
    const int ldoff = lane * 8;             // DMA source offset (shorts)

    // Q fragments: direct coalesced global loads, no LDS round-trip
    short8 qf[4];
    {
        const int t32 = (q0 >> 5) + wid;
#pragma unroll
        for (int kc = 0; kc < 4; ++kc)
            qf[kc] = *(const short8*)&Qh[gbase + ((size_t)t32 * 4 + kc) * 512 + rdoff];
    }

    // stage tiles 0 and 1; wave wid owns K slice wid and V slice wid
#pragma unroll
    for (int tt = 0; tt < 2; ++tt) {
        gl_lds16(&Kh[gbase + ((size_t)(tt * 2 + (wid >> 2)) * 4 + (wid & 3)) * 512 + ldoff],
                 &ks[tt][wid * 512]);
        gl_lds16(&Vth[gbase + ((size_t)tt * 8 + wid) * 512 + ldoff],
                 &vt[tt][wid * 512]);
    }
    __syncthreads();

    f32x16 ctx[2];
    float lsum = 0.f;
#pragma unroll
    for (int i = 0; i < 16; ++i) { ctx[0][i] = 0.f; ctx[1][i] = 0.f; }

    // prologue of the half-pipeline: stH = QK(half 0) = kb0 of tile 0
    f32x16 stH;
#pragma unroll
    for (int i = 0; i < 16; ++i) stH[i] = 0.f;
#pragma unroll
    for (int kc = 0; kc < 4; ++kc) {
        short8 kf = *(const short8*)&ks[0][kc * 512 + rdoff];
        stH = __builtin_amdgcn_mfma_f32_32x32x16_bf16(kf, qf[kc], stH, 0, 0, 0);
    }

    // SM + PV of a 32-key half (scores ST, V slices kb*4.. of vt[buf])
    auto smpv = [&](const f32x16& ST, int buf, int KB) {
#pragma unroll
        for (int ks16 = 0; ks16 < 2; ++ks16) {
            float e0 = __builtin_amdgcn_exp2f(ST[8 * ks16 + 0]);
            float e1 = __builtin_amdgcn_exp2f(ST[8 * ks16 + 1]);
            float e2 = __builtin_amdgcn_exp2f(ST[8 * ks16 + 2]);
            float e3 = __builtin_amdgcn_exp2f(ST[8 * ks16 + 3]);
            float e4 = __builtin_amdgcn_exp2f(ST[8 * ks16 + 4]);
            float e5 = __builtin_amdgcn_exp2f(ST[8 * ks16 + 5]);
            float e6 = __builtin_amdgcn_exp2f(ST[8 * ks16 + 6]);
            float e7 = __builtin_amdgcn_exp2f(ST[8 * ks16 + 7]);
            lsum += ((e0 + e1) + (e2 + e3)) + ((e4 + e5) + (e6 + e7));
            unsigned int w0 = pack_bf16_trunc(e1, e0);
            unsigned int w1 = pack_bf16_trunc(e3, e2);
            unsigned int w2 = pack_bf16_trunc(e5, e4);
            unsigned int w3 = pack_bf16_trunc(e7, e6);
            asm("v_permlane32_swap_b32 %0, %1" : "+v"(w0), "+v"(w2));
            asm("v_permlane32_swap_b32 %0, %1" : "+v"(w1), "+v"(w3));
            union { unsigned int u[4]; short8 s; } pu;
            pu.u[0] = w0; pu.u[1] = w1; pu.u[2] = w2; pu.u[3] = w3;
            const short8 pf = pu.s;
#pragma unroll
            for (int dsub = 0; dsub < 2; ++dsub) {
                short8 vf = *(const short8*)&vt[buf][((KB * 2 + ks16) * 2 + dsub) * 512 + rdoff];
                ctx[dsub] = __builtin_amdgcn_mfma_f32_32x32x16_bf16(
                    pf, vf, ctx[dsub], 0, 0, 0);
            }
        }
    };

    const int NT = S_ / 64;   // 32 tiles, 64 halves
    for (int t = 0; t < NT; ++t) {
        const int cur = t % 3, nxt = (t + 1) % 3, stg = (t + 2) % 3;
        // stage tile t+2 into the ring slot freed at the last barrier
        if (t + 2 < NT) {
            gl_lds16(&Kh[gbase + ((size_t)((t + 2) * 2 + (wid >> 2)) * 4 + (wid & 3)) * 512 + ldoff],
                     &ks[stg][wid * 512]);
            gl_lds16(&Vth[gbase + ((size_t)(t + 2) * 8 + wid) * 512 + ldoff],
                     &vt[stg][wid * 512]);
        }

        // ---- half A (2t): QK(2t+1) in flight over SM+PV(stH) ----
        f32x16 stN;
#pragma unroll
        for (int i = 0; i < 16; ++i) stN[i] = 0.f;
        __builtin_amdgcn_s_setprio(1);
#pragma unroll
        for (int kc = 0; kc < 4; ++kc) {
            short8 kf = *(const short8*)&ks[cur][(4 + kc) * 512 + rdoff];
            stN = __builtin_amdgcn_mfma_f32_32x32x16_bf16(kf, qf[kc], stN, 0, 0, 0);
        }
        __builtin_amdgcn_s_setprio(0);
        smpv(stH, cur, 0);
        stH = stN;

        // ---- half B (2t+1): QK(2t+2) in flight over SM+PV(stH) ----
#pragma unroll
        for (int i = 0; i < 16; ++i) stN[i] = 0.f;
        if (t + 1 < NT) {
            __builtin_amdgcn_s_setprio(1);
#pragma unroll
            for (int kc = 0; kc < 4; ++kc) {
                short8 kf = *(const short8*)&ks[nxt][kc * 512 + rdoff];
                stN = __builtin_amdgcn_mfma_f32_32x32x16_bf16(kf, qf[kc], stN, 0, 0, 0);
            }
            __builtin_amdgcn_s_setprio(0);
        }
        smpv(stH, cur, 1);
        stH = stN;

        __syncthreads();   // all waves done with buf[cur]; staging DMA drained
    }

    // --- epilogue: l redistribution + normalize ---
    // lsum at lane (q=l31, hi) = sum of P[q][keys in hi's half]. Swap gives
    // the other half: other = hi ? a : b.
    float* lsh = (float*)&ks[0][0];
    {
        float a = lsum, bx = lsum;
        asm("v_permlane32_swap_b32 %0, %1" : "+v"(a), "+v"(bx));
        float ltot = lsum + (hi ? a : bx);
        if (hi == 0) lsh[wid * 32 + l31] = ltot;
    }
    __syncthreads();
    // ctx reg r -> q = q0 + wid*32 + (r&3) + 8*(r>>2) + 4*hi, d = dsub*32 + l31
#pragma unroll
    for (int r = 0; r < 16; ++r) {
        int qr = (r & 3) + ((r >> 2) << 3) + hi * 4;
        float inv = 1.f / lsh[wid * 32 + qr];
        int q = q0 + wid * 32 + qr;
        size_t rowbase = ((size_t)b * S_ + q) * E_ + h * D_;
        Ch[rowbase + l31]      = f2bf(ctx[0][r] * inv);
        Ch[rowbase + 32 + l31] = f2bf(ctx[1][r] * inv);
    }
}

// ---------------------------------------------------------------------------
// Kernel 3: output projection OUT = CTX @ Wo + bo (both bf16, Wo transposed).
// R6: same BK=32 / 32KB-LDS occupancy restructure as qkv_gemm.
// ---------------------------------------------------------------------------
__global__ __launch_bounds__(256, 4) void out_proj_kernel(
    const unsigned short* __restrict__ Ch, const unsigned short* __restrict__ Wot,
    const float* __restrict__ bo, float* __restrict__ out)
{
    __shared__ unsigned short As[2][128 * 32];
    __shared__ unsigned short Bs[2][128 * 32];
    const int tid = threadIdx.x;
    const int lane = tid & 63, wid = tid >> 6;
    const int quad = lane >> 4, lc = lane & 15;
    const int wm = wid >> 1, wn = wid & 1;
    const int m0 = blockIdx.y * 128, n0 = blockIdx.x * 128;
    const int srow = lane >> 2;
    const int sch  = (((lane & 3) ^ ((lane >> 2) & 3) ^ ((lane >> 4) & 3))) * 8;
    const int swzr = (lc & 3) ^ ((lc >> 2) & 3);

    f32x4 acc[4][4];
#pragma unroll
    for (int mt = 0; mt < 4; ++mt)
#pragma unroll
        for (int nt = 0; nt < 4; ++nt)
            acc[mt][nt] = (f32x4){0.f, 0.f, 0.f, 0.f};

#pragma unroll
    for (int i = 0; i < 2; ++i) {
        int rw = wid * 32 + i * 16;
        gl_lds16(&Ch[(size_t)(m0 + rw + srow) * E_ + sch], &As[0][rw * 32]);
        gl_lds16(&Wot[(size_t)(n0 + rw + srow) * E_ + sch], &Bs[0][rw * 32]);
    }
    __syncthreads();

    for (int k0 = 0; k0 < E_; k0 += 32) {
        const int cur = (k0 >> 5) & 1;
        if (k0 + 32 < E_) {
#pragma unroll
            for (int i = 0; i < 2; ++i) {
                int rw = wid * 32 + i * 16;
                gl_lds16(&Ch[(size_t)(m0 + rw + srow) * E_ + k0 + 32 + sch], &As[cur ^ 1][rw * 32]);
                gl_lds16(&Wot[(size_t)(n0 + rw + srow) * E_ + k0 + 32 + sch], &Bs[cur ^ 1][rw * 32]);
            }
        }
        short8 a[4], bfr[4];
#pragma unroll
        for (int mt = 0; mt < 4; ++mt)
            a[mt] = *(const short8*)&As[cur][(wm * 64 + mt * 16 + lc) * 32 +
                                            ((quad ^ swzr) << 3)];
#pragma unroll
        for (int nt = 0; nt < 4; ++nt)
            bfr[nt] = *(const short8*)&Bs[cur][(wn * 64 + nt * 16 + lc) * 32 +
                                              ((quad ^ swzr) << 3)];
#pragma unroll
        for (int mt = 0; mt < 4; ++mt)
#pragma unroll
            for (int nt = 0; nt < 4; ++nt)
                acc[mt][nt] = __builtin_amdgcn_mfma_f32_16x16x32_bf16(
                    a[mt], bfr[nt], acc[mt][nt], 0, 0, 0);
        __syncthreads();
    }

#pragma unroll
    for (int mt = 0; mt < 4; ++mt)
#pragma unroll
        for (int nt = 0; nt < 4; ++nt) {
            int n = n0 + wn * 64 + nt * 16 + lc;
            float bb = bo[n];
#pragma unroll
            for (int r = 0; r < 4; ++r) {
                int row = m0 + wm * 64 + mt * 16 + quad * 4 + r;
                out[(size_t)row * E_ + n] = acc[mt][nt][r] + bb;
            }
        }
}

// ---------------------------------------------------------------------------
extern "C" void kernel_launch(void* const* d_in, const int* in_sizes, int n_in,
                              void* d_out, int out_size, void* d_ws, size_t ws_size,
                              hipStream_t stream)
{
    const float* x  = (const float*)d_in[0];
    const float* Wq = (const float*)d_in[1];
    const float* bq = (const float*)d_in[2];
    const float* Wk = (const float*)d_in[3];
    const float* bk = (const float*)d_in[4];
    const float* Wv = (const float*)d_in[5];
    const float* bv = (const float*)d_in[6];
    const float* Wo = (const float*)d_in[7];
    const float* bo = (const float*)d_in[8];
    (void)in_sizes; (void)n_in; (void)out_size; (void)ws_size;

    const size_t N = (size_t)BH_ * S_ * D_;          // 8,388,608
    unsigned short* Wt  = (unsigned short*)d_ws;     // [3072][1024] bf16
    unsigned short* Wot = Wt + (size_t)3072 * 1024;  // [1024][1024]
    unsigned short* Xb  = Wot + (size_t)1024 * 1024; // [8192][1024]
    unsigned short* Qh  = Xb + N;                    // sliced Qg
    unsigned short* Kh  = Qh + N;                    // sliced Kg
    unsigned short* Vth = Kh + N;                    // sliced Vg
    unsigned short* Ch  = Vth + N;                   // [B,S,E]

    xcvt_kernel<<<dim3(4096), 256, 0, stream>>>(x, Xb);
    wtrans_qkv_kernel<<<dim3(32, 2, 48), 256, 0, stream>>>(Wq, Wk, Wv, Wt);
    wtrans_kernel<<<dim3(32, 32, 1), 256, 0, stream>>>(Wo, Wot, E_, E_);

    qkv_gemm_kernel<<<dim3(24, 64), 256, 0, stream>>>(Xb, Wt, bq, bk, bv, Qh, Kh, Vth);
    // grid.x = bh (64): all q-blocks of a bh stay on one XCD (64 % 8 == 0).
    attn_kernel<<<dim3(64, 8), 512, 0, stream>>>(Qh, Kh, Vth, Ch);
    out_proj_kernel<<<dim3(8, 64), 256, 0, stream>>>(Ch, Wot, bo, (float*)d_out);
}

// Round 7
// 268.388 us; speedup vs baseline: 1.0314x; 1.0314x over previous
//
#include <hip/hip_runtime.h>
#include <math.h>

#define B_ 4
#define S_ 2048
#define E_ 1024
#define H_ 16
#define D_ 64
#define BH_ (B_ * H_)

// 1/sqrt(64) * log2(e): folded into Wq/bq so QK^T scores are in exp2 domain
#define SCALE_LOG2E 0.18033688011112042f

typedef short short8 __attribute__((ext_vector_type(8)));   // 8 bf16 (4 VGPR)
typedef float f32x4 __attribute__((ext_vector_type(4)));    // MFMA accumulator
typedef float f32x16 __attribute__((ext_vector_type(16)));  // 32x32 accumulator

static __device__ __forceinline__ unsigned short f2bf(float f) {
    unsigned int u = __float_as_uint(f);
    unsigned int r = (u + 0x7fffu + ((u >> 16) & 1u)) >> 16;
    return (unsigned short)r;
}

// pack two fp32 -> two bf16 (truncation) in one v_perm_b32; low short = lo
static __device__ __forceinline__ unsigned int pack_bf16_trunc(float hi, float lo) {
    return __builtin_amdgcn_perm(__float_as_uint(hi), __float_as_uint(lo), 0x07060302u);
}

// async global->LDS DMA, 16B per lane. LDS dest = base + lane*16 (HW rule).
static __device__ __forceinline__ void gl_lds16(const unsigned short* g, unsigned short* l) {
    __builtin_amdgcn_global_load_lds(
        (const __attribute__((address_space(1))) unsigned int*)g,
        (__attribute__((address_space(3))) unsigned int*)l, 16, 0, 0);
}

// ---------------------------------------------------------------------------
// Attn slice layouts (R2): Qg/Kg [bh][S/32][kc=4][32 rows][2][8];
//                          Vg    [bh][S/64][sv=8][32 drows][2][8].
// GEMM LDS tiles (R7): BM=128 x BK=32 stored as [64 LDS rows][64 shorts]:
// LDS row R packs m-rows (2R, 2R+1); 16B chunk c (0..7) stored at c^(R&7).
// 128B rows => bank depends only on physical chunk; per-16-lane read group
// covers 8 distinct chunks x2 = 2-way = free (same geometry that measured
// ZERO conflicts in R5). [R6 lesson: 64B-row swizzle was 4-way, 6.29M cyc.]
// ---------------------------------------------------------------------------

// ---------------------------------------------------------------------------
// Prep (fused, R7): one launch replaces xcvt + wtrans_qkv + wtrans.
// blocks [0,4096): x fp32->bf16 ; [4096,7168): Wq/Wk/Wv transpose ;
// [7168,8192): Wo transpose.  [R6 lesson: ~60-80us of wall time is
// inter-launch gap; 6 launches -> 4.]
// ---------------------------------------------------------------------------
__global__ __launch_bounds__(256) void prep_kernel(
    const float* __restrict__ x, const float* __restrict__ Wq,
    const float* __restrict__ Wk, const float* __restrict__ Wv,
    const float* __restrict__ Wo,
    unsigned short* __restrict__ Xb, unsigned short* __restrict__ Wt,
    unsigned short* __restrict__ Wot)
{
    const int bid = blockIdx.x;
    if (bid < 4096) {
        // ---- xcvt: 8 elems/thread ----
        size_t i = ((size_t)bid * 256 + threadIdx.x) * 8;
        float4 a = *(const float4*)&x[i];
        float4 b = *(const float4*)&x[i + 4];
        ushort4 u0, u1;
        u0.x = f2bf(a.x); u0.y = f2bf(a.y); u0.z = f2bf(a.z); u0.w = f2bf(a.w);
        u1.x = f2bf(b.x); u1.y = f2bf(b.y); u1.z = f2bf(b.z); u1.w = f2bf(b.w);
        *(ushort4*)&Xb[i]     = u0;
        *(ushort4*)&Xb[i + 4] = u1;
        return;
    }
    __shared__ float t[32][33];
    const int tx = threadIdx.x & 31, ty = threadIdx.x >> 5;
    if (bid < 7168) {
        // ---- wtrans_qkv: fp32 [E][D] -> bf16 [D][E] per head ----
        const int idx = bid - 4096;              // 48 z * (32 x * 2 y)
        const int z = idx >> 6, rem = idx & 63;
        const int r0 = (rem & 31) * 32, c0 = (rem >> 5) * 32;
        const int mtx = z >> 4, h = z & 15;
        const float* s = (mtx == 0 ? Wq : (mtx == 1 ? Wk : Wv)) + (size_t)h * E_ * D_;
        const float scale = (mtx == 0) ? SCALE_LOG2E : 1.0f;
        unsigned short* d = Wt + (size_t)mtx * E_ * E_ + (size_t)h * D_ * E_;
#pragma unroll
        for (int i = 0; i < 4; ++i)
            t[ty + i * 8][tx] = s[(size_t)(r0 + ty + i * 8) * D_ + c0 + tx];
        __syncthreads();
#pragma unroll
        for (int i = 0; i < 4; ++i)
            d[(size_t)(c0 + ty + i * 8) * E_ + r0 + tx] = f2bf(t[tx][ty + i * 8] * scale);
    } else {
        // ---- wtrans: Wo fp32 [E][E] -> bf16 [E][E]^T ----
        const int idx = bid - 7168;
        const int r0 = (idx & 31) * 32, c0 = (idx >> 5) * 32;
#pragma unroll
        for (int i = 0; i < 4; ++i)
            t[ty + i * 8][tx] = Wo[(size_t)(r0 + ty + i * 8) * E_ + c0 + tx];
        __syncthreads();
#pragma unroll
        for (int i = 0; i < 4; ++i)
            Wot[(size_t)(c0 + ty + i * 8) * E_ + r0 + tx] = f2bf(t[tx][ty + i * 8]);
    }
}

// ---------------------------------------------------------------------------
// Kernel 1: fused QKV projection GEMM, C[8192 x 3072] = Xb * W^T (+bias).
// R7: BK=32 (32KB LDS, 4+ blocks/CU) with the packed [64][64] zero-conflict
// tile layout (see header).
// ---------------------------------------------------------------------------
__global__ __launch_bounds__(256, 4) void qkv_gemm_kernel(
    const unsigned short* __restrict__ Xb, const unsigned short* __restrict__ Wt,
    const float* __restrict__ bq, const float* __restrict__ bk,
    const float* __restrict__ bv,
    unsigned short* __restrict__ Qh, unsigned short* __restrict__ Kh,
    unsigned short* __restrict__ Vth)
{
    __shared__ unsigned short As[2][64 * 64];
    __shared__ unsigned short Bs[2][64 * 64];
    const int tid = threadIdx.x;
    const int lane = tid & 63, wid = tid >> 6;
    const int quad = lane >> 4, lc = lane & 15;
    const int wm = wid >> 1, wn = wid & 1;
    const int m0 = blockIdx.y * 128, n0 = blockIdx.x * 128;
    // DMA source decode for packed layout: lane L -> LDS row Rb+(L>>3),
    // phys chunk L&7 -> logical chunk c=(L&7)^(L>>3) -> m-half c>>2, k-chunk c&3
    const int l3 = lane >> 3;
    const int cs = (lane & 7) ^ l3;
    const int mloc = 2 * l3 + (cs >> 2);
    const int koff = (cs & 3) * 8;
    // read-side: m = mb + mt*16 + lc -> R = mb/2 + mt*8 + (lc>>1),
    // chunk c = ((lc&1)<<2)|quad, phys = c ^ ((lc>>1)&7)
    const int rdbase = (lc >> 1) * 64 + (((((lc & 1) << 2) | quad) ^ ((lc >> 1) & 7)) << 3);

    f32x4 acc[4][4];
#pragma unroll
    for (int mt = 0; mt < 4; ++mt)
#pragma unroll
        for (int nt = 0; nt < 4; ++nt)
            acc[mt][nt] = (f32x4){0.f, 0.f, 0.f, 0.f};

    // prologue: stage k0=0 into buffer 0 (2 issues per matrix per wave)
#pragma unroll
    for (int i = 0; i < 2; ++i) {
        int Rb = wid * 16 + i * 8;
        gl_lds16(&Xb[(size_t)(m0 + Rb * 2 + mloc) * E_ + koff], &As[0][Rb * 64]);
        gl_lds16(&Wt[(size_t)(n0 + Rb * 2 + mloc) * E_ + koff], &Bs[0][Rb * 64]);
    }
    __syncthreads();

    for (int k0 = 0; k0 < E_; k0 += 32) {
        const int cur = (k0 >> 5) & 1;
        if (k0 + 32 < E_) {
#pragma unroll
            for (int i = 0; i < 2; ++i) {
                int Rb = wid * 16 + i * 8;
                gl_lds16(&Xb[(size_t)(m0 + Rb * 2 + mloc) * E_ + k0 + 32 + koff],
                         &As[cur ^ 1][Rb * 64]);
                gl_lds16(&Wt[(size_t)(n0 + Rb * 2 + mloc) * E_ + k0 + 32 + koff],
                         &Bs[cur ^ 1][Rb * 64]);
            }
        }
        short8 a[4], bfr[4];
#pragma unroll
        for (int mt = 0; mt < 4; ++mt)
            a[mt] = *(const short8*)&As[cur][(wm * 32 + mt * 8) * 64 + rdbase];
#pragma unroll
        for (int nt = 0; nt < 4; ++nt)
            bfr[nt] = *(const short8*)&Bs[cur][(wn * 32 + nt * 8) * 64 + rdbase];
#pragma unroll
        for (int mt = 0; mt < 4; ++mt)
#pragma unroll
            for (int nt = 0; nt < 4; ++nt)
                acc[mt][nt] = __builtin_amdgcn_mfma_f32_16x16x32_bf16(
                    a[mt], bfr[nt], acc[mt][nt], 0, 0, 0);
        __syncthreads();
    }

    const int nb = n0 + wn * 64;
    const int mtx = nb >> 10;               // 0=Q 1=K 2=V
    const int h = (nb >> 6) & 15;
    const int sg0 = m0 + wm * 64;           // tile rows all in one batch
    const int bb_ = sg0 >> 11;
    const int bhv = bb_ * H_ + h;
    if (mtx < 2) {
        const float bsc = (mtx == 0) ? SCALE_LOG2E : 1.0f;
        const float* bias = (mtx == 0 ? bq : bk) + h * D_;
        unsigned short* Out = (mtx == 0) ? Qh : Kh;
        const size_t obase = (size_t)bhv * (S_ / 32) * 2048;   // 4 slices * 512
#pragma unroll
        for (int nt = 0; nt < 4; ++nt) {
            int d = nt * 16 + lc;
            int hi_ = (lc >> 3) & 1, j = lc & 7;
            float bb = bias[d] * bsc;
#pragma unroll
            for (int mt = 0; mt < 4; ++mt)
#pragma unroll
                for (int r = 0; r < 4; ++r) {
                    int ss = (sg0 + mt * 16 + quad * 4 + r) & (S_ - 1);
                    // Qg/Kg: [bh][s>>5][kc=nt][(s&31)*2 + hi][j]
                    Out[obase + ((size_t)(ss >> 5) * 4 + nt) * 512 +
                        ((ss & 31) * 2 + hi_) * 8 + j] = f2bf(acc[mt][nt][r] + bb);
                }
        }
    } else {
        const float* bias = bv + h * D_;
        const size_t obase = (size_t)bhv * (S_ / 64) * 4096;   // 8 slices * 512
        const int t64 = (sg0 & (S_ - 1)) >> 6;
        const int hi_ = quad >> 1, j0 = (quad & 1) * 4;
#pragma unroll
        for (int nt = 0; nt < 4; ++nt) {
            int d = nt * 16 + lc;
            int dsub = d >> 5, l31d = d & 31;
            float bb = bias[d];
#pragma unroll
            for (int mt = 0; mt < 4; ++mt) {
                // Vg slice sv = mt*2 + dsub ; within: [l31d*2 + hi][j0..j0+3]
                ushort4 u;
                u.x = f2bf(acc[mt][nt][0] + bb);
                u.y = f2bf(acc[mt][nt][1] + bb);
                u.z = f2bf(acc[mt][nt][2] + bb);
                u.w = f2bf(acc[mt][nt][3] + bb);
                *(ushort4*)&Vth[obase + ((size_t)t64 * 8 + mt * 2 + dsub) * 512 +
                                (l31d * 2 + hi_) * 8 + j0] = u;
            }
        }
    }
}

// ---------------------------------------------------------------------------
// Kernel 2: flash attention, no-max streaming softmax, 32x32 swapped-QK route.
// R5 structure (kept): cross-tile software pipeline at 32-key-half
// granularity; 3-buffer ring; 512-thread blocks, 2 blocks/CU, 16 waves/CU.
// ---------------------------------------------------------------------------
__global__ __launch_bounds__(512, 4) void attn_kernel(
    const unsigned short* __restrict__ Qh, const unsigned short* __restrict__ Kh,
    const unsigned short* __restrict__ Vth, unsigned short* __restrict__ Ch)
{
    __shared__ unsigned short ks[3][8 * 512];   // [buf][slice kb*4+kc][512]
    __shared__ unsigned short vt[3][8 * 512];   // [buf][slice sv][512]
    const int tid = threadIdx.x;
    const int lane = tid & 63, wid = tid >> 6;   // wid 0..7
    const int l31 = lane & 31, hi = lane >> 5;
    const int bh = blockIdx.x, b = bh >> 4, h = bh & 15;
    const int q0 = blockIdx.y * 256;
    const size_t gbase = (size_t)bh * (S_ / 32) * 2048;  // per-bh slice base
    const int rdoff = (l31 * 2 + hi) * 8;   // within-slice fragment offset
    const int ldoff = lane * 8;             // DMA source offset (shorts)

    // Q fragments: direct coalesced global loads, no LDS round-trip
    short8 qf[4];
    {
        const int t32 = (q0 >> 5) + wid;
#pragma unroll
        for (int kc = 0; kc < 4; ++kc)
            qf[kc] = *(const short8*)&Qh[gbase + ((size_t)t32 * 4 + kc) * 512 + rdoff];
    }

    // stage tiles 0 and 1; wave wid owns K slice wid and V slice wid
#pragma unroll
    for (int tt = 0; tt < 2; ++tt) {
        gl_lds16(&Kh[gbase + ((size_t)(tt * 2 + (wid >> 2)) * 4 + (wid & 3)) * 512 + ldoff],
                 &ks[tt][wid * 512]);
        gl_lds16(&Vth[gbase + ((size_t)tt * 8 + wid) * 512 + ldoff],
                 &vt[tt][wid * 512]);
    }
    __syncthreads();

    f32x16 ctx[2];
    float lsum = 0.f;
#pragma unroll
    for (int i = 0; i < 16; ++i) { ctx[0][i] = 0.f; ctx[1][i] = 0.f; }

    // prologue of the half-pipeline: stH = QK(half 0) = kb0 of tile 0
    f32x16 stH;
#pragma unroll
    for (int i = 0; i < 16; ++i) stH[i] = 0.f;
#pragma unroll
    for (int kc = 0; kc < 4; ++kc) {
        short8 kf = *(const short8*)&ks[0][kc * 512 + rdoff];
        stH = __builtin_amdgcn_mfma_f32_32x32x16_bf16(kf, qf[kc], stH, 0, 0, 0);
    }

    // SM + PV of a 32-key half (scores ST, V slices kb*4.. of vt[buf])
    auto smpv = [&](const f32x16& ST, int buf, int KB) {
#pragma unroll
        for (int ks16 = 0; ks16 < 2; ++ks16) {
            float e0 = __builtin_amdgcn_exp2f(ST[8 * ks16 + 0]);
            float e1 = __builtin_amdgcn_exp2f(ST[8 * ks16 + 1]);
            float e2 = __builtin_amdgcn_exp2f(ST[8 * ks16 + 2]);
            float e3 = __builtin_amdgcn_exp2f(ST[8 * ks16 + 3]);
            float e4 = __builtin_amdgcn_exp2f(ST[8 * ks16 + 4]);
            float e5 = __builtin_amdgcn_exp2f(ST[8 * ks16 + 5]);
            float e6 = __builtin_amdgcn_exp2f(ST[8 * ks16 + 6]);
            float e7 = __builtin_amdgcn_exp2f(ST[8 * ks16 + 7]);
            lsum += ((e0 + e1) + (e2 + e3)) + ((e4 + e5) + (e6 + e7));
            unsigned int w0 = pack_bf16_trunc(e1, e0);
            unsigned int w1 = pack_bf16_trunc(e3, e2);
            unsigned int w2 = pack_bf16_trunc(e5, e4);
            unsigned int w3 = pack_bf16_trunc(e7, e6);
            asm("v_permlane32_swap_b32 %0, %1" : "+v"(w0), "+v"(w2));
            asm("v_permlane32_swap_b32 %0, %1" : "+v"(w1), "+v"(w3));
            union { unsigned int u[4]; short8 s; } pu;
            pu.u[0] = w0; pu.u[1] = w1; pu.u[2] = w2; pu.u[3] = w3;
            const short8 pf = pu.s;
#pragma unroll
            for (int dsub = 0; dsub < 2; ++dsub) {
                short8 vf = *(const short8*)&vt[buf][((KB * 2 + ks16) * 2 + dsub) * 512 + rdoff];
                ctx[dsub] = __builtin_amdgcn_mfma_f32_32x32x16_bf16(
                    pf, vf, ctx[dsub], 0, 0, 0);
            }
        }
    };

    const int NT = S_ / 64;   // 32 tiles, 64 halves
    for (int t = 0; t < NT; ++t) {
        const int cur = t % 3, nxt = (t + 1) % 3, stg = (t + 2) % 3;
        // stage tile t+2 into the ring slot freed at the last barrier
        if (t + 2 < NT) {
            gl_lds16(&Kh[gbase + ((size_t)((t + 2) * 2 + (wid >> 2)) * 4 + (wid & 3)) * 512 + ldoff],
                     &ks[stg][wid * 512]);
            gl_lds16(&Vth[gbase + ((size_t)(t + 2) * 8 + wid) * 512 + ldoff],
                     &vt[stg][wid * 512]);
        }

        // ---- half A (2t): QK(2t+1) in flight over SM+PV(stH) ----
        f32x16 stN;
#pragma unroll
        for (int i = 0; i < 16; ++i) stN[i] = 0.f;
        __builtin_amdgcn_s_setprio(1);
#pragma unroll
        for (int kc = 0; kc < 4; ++kc) {
            short8 kf = *(const short8*)&ks[cur][(4 + kc) * 512 + rdoff];
            stN = __builtin_amdgcn_mfma_f32_32x32x16_bf16(kf, qf[kc], stN, 0, 0, 0);
        }
        __builtin_amdgcn_s_setprio(0);
        smpv(stH, cur, 0);
        stH = stN;

        // ---- half B (2t+1): QK(2t+2) in flight over SM+PV(stH) ----
#pragma unroll
        for (int i = 0; i < 16; ++i) stN[i] = 0.f;
        if (t + 1 < NT) {
            __builtin_amdgcn_s_setprio(1);
#pragma unroll
            for (int kc = 0; kc < 4; ++kc) {
                short8 kf = *(const short8*)&ks[nxt][kc * 512 + rdoff];
                stN = __builtin_amdgcn_mfma_f32_32x32x16_bf16(kf, qf[kc], stN, 0, 0, 0);
            }
            __builtin_amdgcn_s_setprio(0);
        }
        smpv(stH, cur, 1);
        stH = stN;

        __syncthreads();   // all waves done with buf[cur]; staging DMA drained
    }

    // --- epilogue: l redistribution + normalize ---
    // lsum at lane (q=l31, hi) = sum of P[q][keys in hi's half]. Swap gives
    // the other half: other = hi ? a : b.
    float* lsh = (float*)&ks[0][0];
    {
        float a = lsum, bx = lsum;
        asm("v_permlane32_swap_b32 %0, %1" : "+v"(a), "+v"(bx));
        float ltot = lsum + (hi ? a : bx);
        if (hi == 0) lsh[wid * 32 + l31] = ltot;
    }
    __syncthreads();
    // ctx reg r -> q = q0 + wid*32 + (r&3) + 8*(r>>2) + 4*hi, d = dsub*32 + l31
#pragma unroll
    for (int r = 0; r < 16; ++r) {
        int qr = (r & 3) + ((r >> 2) << 3) + hi * 4;
        float inv = 1.f / lsh[wid * 32 + qr];
        int q = q0 + wid * 32 + qr;
        size_t rowbase = ((size_t)b * S_ + q) * E_ + h * D_;
        Ch[rowbase + l31]      = f2bf(ctx[0][r] * inv);
        Ch[rowbase + 32 + l31] = f2bf(ctx[1][r] * inv);
    }
}

// ---------------------------------------------------------------------------
// Kernel 3: output projection OUT = CTX @ Wo + bo (both bf16, Wo transposed).
// R7: same packed [64][64] zero-conflict BK=32 structure as qkv_gemm.
// ---------------------------------------------------------------------------
__global__ __launch_bounds__(256, 4) void out_proj_kernel(
    const unsigned short* __restrict__ Ch, const unsigned short* __restrict__ Wot,
    const float* __restrict__ bo, float* __restrict__ out)
{
    __shared__ unsigned short As[2][64 * 64];
    __shared__ unsigned short Bs[2][64 * 64];
    const int tid = threadIdx.x;
    const int lane = tid & 63, wid = tid >> 6;
    const int quad = lane >> 4, lc = lane & 15;
    const int wm = wid >> 1, wn = wid & 1;
    const int m0 = blockIdx.y * 128, n0 = blockIdx.x * 128;
    const int l3 = lane >> 3;
    const int cs = (lane & 7) ^ l3;
    const int mloc = 2 * l3 + (cs >> 2);
    const int koff = (cs & 3) * 8;
    const int rdbase = (lc >> 1) * 64 + (((((lc & 1) << 2) | quad) ^ ((lc >> 1) & 7)) << 3);

    f32x4 acc[4][4];
#pragma unroll
    for (int mt = 0; mt < 4; ++mt)
#pragma unroll
        for (int nt = 0; nt < 4; ++nt)
            acc[mt][nt] = (f32x4){0.f, 0.f, 0.f, 0.f};

#pragma unroll
    for (int i = 0; i < 2; ++i) {
        int Rb = wid * 16 + i * 8;
        gl_lds16(&Ch[(size_t)(m0 + Rb * 2 + mloc) * E_ + koff], &As[0][Rb * 64]);
        gl_lds16(&Wot[(size_t)(n0 + Rb * 2 + mloc) * E_ + koff], &Bs[0][Rb * 64]);
    }
    __syncthreads();

    for (int k0 = 0; k0 < E_; k0 += 32) {
        const int cur = (k0 >> 5) & 1;
        if (k0 + 32 < E_) {
#pragma unroll
            for (int i = 0; i < 2; ++i) {
                int Rb = wid * 16 + i * 8;
                gl_lds16(&Ch[(size_t)(m0 + Rb * 2 + mloc) * E_ + k0 + 32 + koff],
                         &As[cur ^ 1][Rb * 64]);
                gl_lds16(&Wot[(size_t)(n0 + Rb * 2 + mloc) * E_ + k0 + 32 + koff],
                         &Bs[cur ^ 1][Rb * 64]);
            }
        }
        short8 a[4], bfr[4];
#pragma unroll
        for (int mt = 0; mt < 4; ++mt)
            a[mt] = *(const short8*)&As[cur][(wm * 32 + mt * 8) * 64 + rdbase];
#pragma unroll
        for (int nt = 0; nt < 4; ++nt)
            bfr[nt] = *(const short8*)&Bs[cur][(wn * 32 + nt * 8) * 64 + rdbase];
#pragma unroll
        for (int mt = 0; mt < 4; ++mt)
#pragma unroll
            for (int nt = 0; nt < 4; ++nt)
                acc[mt][nt] = __builtin_amdgcn_mfma_f32_16x16x32_bf16(
                    a[mt], bfr[nt], acc[mt][nt], 0, 0, 0);
        __syncthreads();
    }

#pragma unroll
    for (int mt = 0; mt < 4; ++mt)
#pragma unroll
        for (int nt = 0; nt < 4; ++nt) {
            int n = n0 + wn * 64 + nt * 16 + lc;
            float bb = bo[n];
#pragma unroll
            for (int r = 0; r < 4; ++r) {
                int row = m0 + wm * 64 + mt * 16 + quad * 4 + r;
                out[(size_t)row * E_ + n] = acc[mt][nt][r] + bb;
            }
        }
}

// ---------------------------------------------------------------------------
extern "C" void kernel_launch(void* const* d_in, const int* in_sizes, int n_in,
                              void* d_out, int out_size, void* d_ws, size_t ws_size,
                              hipStream_t stream)
{
    const float* x  = (const float*)d_in[0];
    const float* Wq = (const float*)d_in[1];
    const float* bq = (const float*)d_in[2];
    const float* Wk = (const float*)d_in[3];
    const float* bk = (const float*)d_in[4];
    const float* Wv = (const float*)d_in[5];
    const float* bv = (const float*)d_in[6];
    const float* Wo = (const float*)d_in[7];
    const float* bo = (const float*)d_in[8];
    (void)in_sizes; (void)n_in; (void)out_size; (void)ws_size;

    const size_t N = (size_t)BH_ * S_ * D_;          // 8,388,608
    unsigned short* Wt  = (unsigned short*)d_ws;     // [3072][1024] bf16
    unsigned short* Wot = Wt + (size_t)3072 * 1024;  // [1024][1024]
    unsigned short* Xb  = Wot + (size_t)1024 * 1024; // [8192][1024]
    unsigned short* Qh  = Xb + N;                    // sliced Qg
    unsigned short* Kh  = Qh + N;                    // sliced Kg
    unsigned short* Vth = Kh + N;                    // sliced Vg
    unsigned short* Ch  = Vth + N;                   // [B,S,E]

    prep_kernel<<<dim3(8192), 256, 0, stream>>>(x, Wq, Wk, Wv, Wo, Xb, Wt, Wot);
    qkv_gemm_kernel<<<dim3(24, 64), 256, 0, stream>>>(Xb, Wt, bq, bk, bv, Qh, Kh, Vth);
    // grid.x = bh (64): all q-blocks of a bh stay on one XCD (64 % 8 == 0).
    attn_kernel<<<dim3(64, 8), 512, 0, stream>>>(Qh, Kh, Vth, Ch);
    out_proj_kernel<<<dim3(8, 64), 256, 0, stream>>>(Ch, Wot, bo, (float*)d_out);
}

// Round 8
// 264.556 us; speedup vs baseline: 1.0463x; 1.0145x over previous
//
#include <hip/hip_runtime.h>
#include <math.h>

#define B_ 4
#define S_ 2048
#define E_ 1024
#define H_ 16
#define D_ 64
#define BH_ (B_ * H_)

// 1/sqrt(64) * log2(e): folded into Wq/bq so QK^T scores are in exp2 domain
#define SCALE_LOG2E 0.18033688011112042f

typedef short short8 __attribute__((ext_vector_type(8)));   // 8 bf16 (4 VGPR)
typedef float f32x4 __attribute__((ext_vector_type(4)));    // MFMA accumulator
typedef float f32x16 __attribute__((ext_vector_type(16)));  // 32x32 accumulator

static __device__ __forceinline__ unsigned short f2bf(float f) {
    unsigned int u = __float_as_uint(f);
    unsigned int r = (u + 0x7fffu + ((u >> 16) & 1u)) >> 16;
    return (unsigned short)r;
}

// pack two fp32 -> two bf16 (truncation) in one v_perm_b32; low short = lo
static __device__ __forceinline__ unsigned int pack_bf16_trunc(float hi, float lo) {
    return __builtin_amdgcn_perm(__float_as_uint(hi), __float_as_uint(lo), 0x07060302u);
}

// async global->LDS DMA, 16B per lane. LDS dest = base + lane*16 (HW rule).
static __device__ __forceinline__ void gl_lds16(const unsigned short* g, unsigned short* l) {
    __builtin_amdgcn_global_load_lds(
        (const __attribute__((address_space(1))) unsigned int*)g,
        (__attribute__((address_space(3))) unsigned int*)l, 16, 0, 0);
}

// ---------------------------------------------------------------------------
// Attn slice layouts (R2): Qg/Kg [bh][S/32][kc=4][32 rows][2][8];
//                          Vg    [bh][S/64][sv=8][32 drows][2][8].
// GEMM LDS tiles (R7): BM=128 x BK=32 stored as [64 LDS rows][64 shorts]:
// LDS row R packs m-rows (2R, 2R+1); 16B chunk c stored at c^(R&7). 128B rows
// => 2-way max on reads (free).
// R8 GEMM sync protocol (T3/T4 graft): 3-buffer ring, stage 2 tiles ahead.
// iter t: issue tile t+2 (4 loads/wave) -> s_waitcnt vmcnt(8) (= tile t's
// loads done; t+1/t+2's 8 stay IN FLIGHT across the barrier) -> raw s_barrier
// -> ds_read slot t%3 + MFMA -> raw s_barrier (protects slot (t+3)%3 == t%3
// from next iter's DMA). No vmcnt(0) drain in the main loop -- the drain at
// __syncthreads was the ~68% idle [R7 PMC: MfmaUtil 28, occ 32, dur flat
// after conflict fix].
// ---------------------------------------------------------------------------

// ---------------------------------------------------------------------------
// Prep (fused, R7): one launch replaces xcvt + wtrans_qkv + wtrans.
// blocks [0,4096): x fp32->bf16 ; [4096,7168): Wq/Wk/Wv transpose ;
// [7168,8192): Wo transpose.
// ---------------------------------------------------------------------------
__global__ __launch_bounds__(256) void prep_kernel(
    const float* __restrict__ x, const float* __restrict__ Wq,
    const float* __restrict__ Wk, const float* __restrict__ Wv,
    const float* __restrict__ Wo,
    unsigned short* __restrict__ Xb, unsigned short* __restrict__ Wt,
    unsigned short* __restrict__ Wot)
{
    const int bid = blockIdx.x;
    if (bid < 4096) {
        // ---- xcvt: 8 elems/thread ----
        size_t i = ((size_t)bid * 256 + threadIdx.x) * 8;
        float4 a = *(const float4*)&x[i];
        float4 b = *(const float4*)&x[i + 4];
        ushort4 u0, u1;
        u0.x = f2bf(a.x); u0.y = f2bf(a.y); u0.z = f2bf(a.z); u0.w = f2bf(a.w);
        u1.x = f2bf(b.x); u1.y = f2bf(b.y); u1.z = f2bf(b.z); u1.w = f2bf(b.w);
        *(ushort4*)&Xb[i]     = u0;
        *(ushort4*)&Xb[i + 4] = u1;
        return;
    }
    __shared__ float t[32][33];
    const int tx = threadIdx.x & 31, ty = threadIdx.x >> 5;
    if (bid < 7168) {
        // ---- wtrans_qkv: fp32 [E][D] -> bf16 [D][E] per head ----
        const int idx = bid - 4096;              // 48 z * (32 x * 2 y)
        const int z = idx >> 6, rem = idx & 63;
        const int r0 = (rem & 31) * 32, c0 = (rem >> 5) * 32;
        const int mtx = z >> 4, h = z & 15;
        const float* s = (mtx == 0 ? Wq : (mtx == 1 ? Wk : Wv)) + (size_t)h * E_ * D_;
        const float scale = (mtx == 0) ? SCALE_LOG2E : 1.0f;
        unsigned short* d = Wt + (size_t)mtx * E_ * E_ + (size_t)h * D_ * E_;
#pragma unroll
        for (int i = 0; i < 4; ++i)
            t[ty + i * 8][tx] = s[(size_t)(r0 + ty + i * 8) * D_ + c0 + tx];
        __syncthreads();
#pragma unroll
        for (int i = 0; i < 4; ++i)
            d[(size_t)(c0 + ty + i * 8) * E_ + r0 + tx] = f2bf(t[tx][ty + i * 8] * scale);
    } else {
        // ---- wtrans: Wo fp32 [E][E] -> bf16 [E][E]^T ----
        const int idx = bid - 7168;
        const int r0 = (idx & 31) * 32, c0 = (idx >> 5) * 32;
#pragma unroll
        for (int i = 0; i < 4; ++i)
            t[ty + i * 8][tx] = Wo[(size_t)(r0 + ty + i * 8) * E_ + c0 + tx];
        __syncthreads();
#pragma unroll
        for (int i = 0; i < 4; ++i)
            Wot[(size_t)(c0 + ty + i * 8) * E_ + r0 + tx] = f2bf(t[tx][ty + i * 8]);
    }
}

// ---------------------------------------------------------------------------
// Kernel 1: fused QKV projection GEMM, C[8192 x 3072] = Xb * W^T (+bias).
// R8: counted-vmcnt ring pipeline (see header). 48KB LDS, 3 blocks/CU.
// ---------------------------------------------------------------------------
__global__ __launch_bounds__(256, 3) void qkv_gemm_kernel(
    const unsigned short* __restrict__ Xb, const unsigned short* __restrict__ Wt,
    const float* __restrict__ bq, const float* __restrict__ bk,
    const float* __restrict__ bv,
    unsigned short* __restrict__ Qh, unsigned short* __restrict__ Kh,
    unsigned short* __restrict__ Vth)
{
    __shared__ unsigned short As[3][64 * 64];
    __shared__ unsigned short Bs[3][64 * 64];
    const int tid = threadIdx.x;
    const int lane = tid & 63, wid = tid >> 6;
    const int quad = lane >> 4, lc = lane & 15;
    const int wm = wid >> 1, wn = wid & 1;
    const int m0 = blockIdx.y * 128, n0 = blockIdx.x * 128;
    // DMA source decode for packed layout (R7): lane L -> LDS row Rb+(L>>3),
    // phys chunk L&7 -> logical chunk c=(L&7)^(L>>3) -> m-half c>>2, k-chunk c&3
    const int l3 = lane >> 3;
    const int cs = (lane & 7) ^ l3;
    const int mloc = 2 * l3 + (cs >> 2);
    const int koff = (cs & 3) * 8;
    // read-side: m = mb + mt*16 + lc -> R = mb/2 + mt*8 + (lc>>1),
    // chunk c = ((lc&1)<<2)|quad, phys = c ^ ((lc>>1)&7)
    const int rdbase = (lc >> 1) * 64 + (((((lc & 1) << 2) | quad) ^ ((lc >> 1) & 7)) << 3);

    f32x4 acc[4][4];
#pragma unroll
    for (int mt = 0; mt < 4; ++mt)
#pragma unroll
        for (int nt = 0; nt < 4; ++nt)
            acc[mt][nt] = (f32x4){0.f, 0.f, 0.f, 0.f};

    // prologue: stage tiles 0 and 1 (slots 0,1); NO wait -- iter 0's vmcnt
    // gates on tile 0.
#pragma unroll
    for (int tt = 0; tt < 2; ++tt)
#pragma unroll
        for (int i = 0; i < 2; ++i) {
            int Rb = wid * 16 + i * 8;
            gl_lds16(&Xb[(size_t)(m0 + Rb * 2 + mloc) * E_ + tt * 32 + koff], &As[tt][Rb * 64]);
            gl_lds16(&Wt[(size_t)(n0 + Rb * 2 + mloc) * E_ + tt * 32 + koff], &Bs[tt][Rb * 64]);
        }

    const int NT = E_ / 32;   // 32 K-tiles
    for (int t = 0; t < NT; ++t) {
        const int cur = t % 3, stg = (t + 2) % 3;
        if (t + 2 < NT) {
            const int ko = (t + 2) * 32;
#pragma unroll
            for (int i = 0; i < 2; ++i) {
                int Rb = wid * 16 + i * 8;
                gl_lds16(&Xb[(size_t)(m0 + Rb * 2 + mloc) * E_ + ko + koff], &As[stg][Rb * 64]);
                gl_lds16(&Wt[(size_t)(n0 + Rb * 2 + mloc) * E_ + ko + koff], &Bs[stg][Rb * 64]);
            }
            asm volatile("s_waitcnt vmcnt(8)" ::: "memory");   // tile t done
        } else if (t + 1 < NT) {
            asm volatile("s_waitcnt vmcnt(4)" ::: "memory");   // tile t done
        } else {
            asm volatile("s_waitcnt vmcnt(0)" ::: "memory");   // last tile
        }
        __builtin_amdgcn_s_barrier();          // all waves' tile-t DMA landed
        __builtin_amdgcn_sched_barrier(0);

        short8 a[4], bfr[4];
#pragma unroll
        for (int mt = 0; mt < 4; ++mt)
            a[mt] = *(const short8*)&As[cur][(wm * 32 + mt * 8) * 64 + rdbase];
#pragma unroll
        for (int nt = 0; nt < 4; ++nt)
            bfr[nt] = *(const short8*)&Bs[cur][(wn * 32 + nt * 8) * 64 + rdbase];
#pragma unroll
        for (int mt = 0; mt < 4; ++mt)
#pragma unroll
            for (int nt = 0; nt < 4; ++nt)
                acc[mt][nt] = __builtin_amdgcn_mfma_f32_16x16x32_bf16(
                    a[mt], bfr[nt], acc[mt][nt], 0, 0, 0);

        __builtin_amdgcn_sched_barrier(0);
        __builtin_amdgcn_s_barrier();          // slot t%3 free for iter t+1 DMA
    }

    const int nb = n0 + wn * 64;
    const int mtx = nb >> 10;               // 0=Q 1=K 2=V
    const int h = (nb >> 6) & 15;
    const int sg0 = m0 + wm * 64;           // tile rows all in one batch
    const int bb_ = sg0 >> 11;
    const int bhv = bb_ * H_ + h;
    if (mtx < 2) {
        const float bsc = (mtx == 0) ? SCALE_LOG2E : 1.0f;
        const float* bias = (mtx == 0 ? bq : bk) + h * D_;
        unsigned short* Out = (mtx == 0) ? Qh : Kh;
        const size_t obase = (size_t)bhv * (S_ / 32) * 2048;   // 4 slices * 512
#pragma unroll
        for (int nt = 0; nt < 4; ++nt) {
            int d = nt * 16 + lc;
            int hi_ = (lc >> 3) & 1, j = lc & 7;
            float bb = bias[d] * bsc;
#pragma unroll
            for (int mt = 0; mt < 4; ++mt)
#pragma unroll
                for (int r = 0; r < 4; ++r) {
                    int ss = (sg0 + mt * 16 + quad * 4 + r) & (S_ - 1);
                    // Qg/Kg: [bh][s>>5][kc=nt][(s&31)*2 + hi][j]
                    Out[obase + ((size_t)(ss >> 5) * 4 + nt) * 512 +
                        ((ss & 31) * 2 + hi_) * 8 + j] = f2bf(acc[mt][nt][r] + bb);
                }
        }
    } else {
        const float* bias = bv + h * D_;
        const size_t obase = (size_t)bhv * (S_ / 64) * 4096;   // 8 slices * 512
        const int t64 = (sg0 & (S_ - 1)) >> 6;
        const int hi_ = quad >> 1, j0 = (quad & 1) * 4;
#pragma unroll
        for (int nt = 0; nt < 4; ++nt) {
            int d = nt * 16 + lc;
            int dsub = d >> 5, l31d = d & 31;
            float bb = bias[d];
#pragma unroll
            for (int mt = 0; mt < 4; ++mt) {
                // Vg slice sv = mt*2 + dsub ; within: [l31d*2 + hi][j0..j0+3]
                ushort4 u;
                u.x = f2bf(acc[mt][nt][0] + bb);
                u.y = f2bf(acc[mt][nt][1] + bb);
                u.z = f2bf(acc[mt][nt][2] + bb);
                u.w = f2bf(acc[mt][nt][3] + bb);
                *(ushort4*)&Vth[obase + ((size_t)t64 * 8 + mt * 2 + dsub) * 512 +
                                (l31d * 2 + hi_) * 8 + j0] = u;
            }
        }
    }
}

// ---------------------------------------------------------------------------
// Kernel 2: flash attention, no-max streaming softmax, 32x32 swapped-QK route.
// R5 structure (kept): cross-tile software pipeline at 32-key-half
// granularity; 3-buffer ring; 512-thread blocks, 2 blocks/CU, 16 waves/CU.
// ---------------------------------------------------------------------------
__global__ __launch_bounds__(512, 4) void attn_kernel(
    const unsigned short* __restrict__ Qh, const unsigned short* __restrict__ Kh,
    const unsigned short* __restrict__ Vth, unsigned short* __restrict__ Ch)
{
    __shared__ unsigned short ks[3][8 * 512];   // [buf][slice kb*4+kc][512]
    __shared__ unsigned short vt[3][8 * 512];   // [buf][slice sv][512]
    const int tid = threadIdx.x;
    const int lane = tid & 63, wid = tid >> 6;   // wid 0..7
    const int l31 = lane & 31, hi = lane >> 5;
    const int bh = blockIdx.x, b = bh >> 4, h = bh & 15;
    const int q0 = blockIdx.y * 256;
    const size_t gbase = (size_t)bh * (S_ / 32) * 2048;  // per-bh slice base
    const int rdoff = (l31 * 2 + hi) * 8;   // within-slice fragment offset
    const int ldoff = lane * 8;             // DMA source offset (shorts)

    // Q fragments: direct coalesced global loads, no LDS round-trip
    short8 qf[4];
    {
        const int t32 = (q0 >> 5) + wid;
#pragma unroll
        for (int kc = 0; kc < 4; ++kc)
            qf[kc] = *(const short8*)&Qh[gbase + ((size_t)t32 * 4 + kc) * 512 + rdoff];
    }

    // stage tiles 0 and 1; wave wid owns K slice wid and V slice wid
#pragma unroll
    for (int tt = 0; tt < 2; ++tt) {
        gl_lds16(&Kh[gbase + ((size_t)(tt * 2 + (wid >> 2)) * 4 + (wid & 3)) * 512 + ldoff],
                 &ks[tt][wid * 512]);
        gl_lds16(&Vth[gbase + ((size_t)tt * 8 + wid) * 512 + ldoff],
                 &vt[tt][wid * 512]);
    }
    __syncthreads();

    f32x16 ctx[2];
    float lsum = 0.f;
#pragma unroll
    for (int i = 0; i < 16; ++i) { ctx[0][i] = 0.f; ctx[1][i] = 0.f; }

    // prologue of the half-pipeline: stH = QK(half 0) = kb0 of tile 0
    f32x16 stH;
#pragma unroll
    for (int i = 0; i < 16; ++i) stH[i] = 0.f;
#pragma unroll
    for (int kc = 0; kc < 4; ++kc) {
        short8 kf = *(const short8*)&ks[0][kc * 512 + rdoff];
        stH = __builtin_amdgcn_mfma_f32_32x32x16_bf16(kf, qf[kc], stH, 0, 0, 0);
    }

    // SM + PV of a 32-key half (scores ST, V slices kb*4.. of vt[buf])
    auto smpv = [&](const f32x16& ST, int buf, int KB) {
#pragma unroll
        for (int ks16 = 0; ks16 < 2; ++ks16) {
            float e0 = __builtin_amdgcn_exp2f(ST[8 * ks16 + 0]);
            float e1 = __builtin_amdgcn_exp2f(ST[8 * ks16 + 1]);
            float e2 = __builtin_amdgcn_exp2f(ST[8 * ks16 + 2]);
            float e3 = __builtin_amdgcn_exp2f(ST[8 * ks16 + 3]);
            float e4 = __builtin_amdgcn_exp2f(ST[8 * ks16 + 4]);
            float e5 = __builtin_amdgcn_exp2f(ST[8 * ks16 + 5]);
            float e6 = __builtin_amdgcn_exp2f(ST[8 * ks16 + 6]);
            float e7 = __builtin_amdgcn_exp2f(ST[8 * ks16 + 7]);
            lsum += ((e0 + e1) + (e2 + e3)) + ((e4 + e5) + (e6 + e7));
            unsigned int w0 = pack_bf16_trunc(e1, e0);
            unsigned int w1 = pack_bf16_trunc(e3, e2);
            unsigned int w2 = pack_bf16_trunc(e5, e4);
            unsigned int w3 = pack_bf16_trunc(e7, e6);
            asm("v_permlane32_swap_b32 %0, %1" : "+v"(w0), "+v"(w2));
            asm("v_permlane32_swap_b32 %0, %1" : "+v"(w1), "+v"(w3));
            union { unsigned int u[4]; short8 s; } pu;
            pu.u[0] = w0; pu.u[1] = w1; pu.u[2] = w2; pu.u[3] = w3;
            const short8 pf = pu.s;
#pragma unroll
            for (int dsub = 0; dsub < 2; ++dsub) {
                short8 vf = *(const short8*)&vt[buf][((KB * 2 + ks16) * 2 + dsub) * 512 + rdoff];
                ctx[dsub] = __builtin_amdgcn_mfma_f32_32x32x16_bf16(
                    pf, vf, ctx[dsub], 0, 0, 0);
            }
        }
    };

    const int NT = S_ / 64;   // 32 tiles, 64 halves
    for (int t = 0; t < NT; ++t) {
        const int cur = t % 3, nxt = (t + 1) % 3, stg = (t + 2) % 3;
        // stage tile t+2 into the ring slot freed at the last barrier
        if (t + 2 < NT) {
            gl_lds16(&Kh[gbase + ((size_t)((t + 2) * 2 + (wid >> 2)) * 4 + (wid & 3)) * 512 + ldoff],
                     &ks[stg][wid * 512]);
            gl_lds16(&Vth[gbase + ((size_t)(t + 2) * 8 + wid) * 512 + ldoff],
                     &vt[stg][wid * 512]);
        }

        // ---- half A (2t): QK(2t+1) in flight over SM+PV(stH) ----
        f32x16 stN;
#pragma unroll
        for (int i = 0; i < 16; ++i) stN[i] = 0.f;
        __builtin_amdgcn_s_setprio(1);
#pragma unroll
        for (int kc = 0; kc < 4; ++kc) {
            short8 kf = *(const short8*)&ks[cur][(4 + kc) * 512 + rdoff];
            stN = __builtin_amdgcn_mfma_f32_32x32x16_bf16(kf, qf[kc], stN, 0, 0, 0);
        }
        __builtin_amdgcn_s_setprio(0);
        smpv(stH, cur, 0);
        stH = stN;

        // ---- half B (2t+1): QK(2t+2) in flight over SM+PV(stH) ----
#pragma unroll
        for (int i = 0; i < 16; ++i) stN[i] = 0.f;
        if (t + 1 < NT) {
            __builtin_amdgcn_s_setprio(1);
#pragma unroll
            for (int kc = 0; kc < 4; ++kc) {
                short8 kf = *(const short8*)&ks[nxt][kc * 512 + rdoff];
                stN = __builtin_amdgcn_mfma_f32_32x32x16_bf16(kf, qf[kc], stN, 0, 0, 0);
            }
            __builtin_amdgcn_s_setprio(0);
        }
        smpv(stH, cur, 1);
        stH = stN;

        __syncthreads();   // all waves done with buf[cur]; staging DMA drained
    }

    // --- epilogue: l redistribution + normalize ---
    // lsum at lane (q=l31, hi) = sum of P[q][keys in hi's half]. Swap gives
    // the other half: other = hi ? a : b.
    float* lsh = (float*)&ks[0][0];
    {
        float a = lsum, bx = lsum;
        asm("v_permlane32_swap_b32 %0, %1" : "+v"(a), "+v"(bx));
        float ltot = lsum + (hi ? a : bx);
        if (hi == 0) lsh[wid * 32 + l31] = ltot;
    }
    __syncthreads();
    // ctx reg r -> q = q0 + wid*32 + (r&3) + 8*(r>>2) + 4*hi, d = dsub*32 + l31
#pragma unroll
    for (int r = 0; r < 16; ++r) {
        int qr = (r & 3) + ((r >> 2) << 3) + hi * 4;
        float inv = 1.f / lsh[wid * 32 + qr];
        int q = q0 + wid * 32 + qr;
        size_t rowbase = ((size_t)b * S_ + q) * E_ + h * D_;
        Ch[rowbase + l31]      = f2bf(ctx[0][r] * inv);
        Ch[rowbase + 32 + l31] = f2bf(ctx[1][r] * inv);
    }
}

// ---------------------------------------------------------------------------
// Kernel 3: output projection OUT = CTX @ Wo + bo (both bf16, Wo transposed).
// R8: same counted-vmcnt ring pipeline as qkv_gemm.
// ---------------------------------------------------------------------------
__global__ __launch_bounds__(256, 3) void out_proj_kernel(
    const unsigned short* __restrict__ Ch, const unsigned short* __restrict__ Wot,
    const float* __restrict__ bo, float* __restrict__ out)
{
    __shared__ unsigned short As[3][64 * 64];
    __shared__ unsigned short Bs[3][64 * 64];
    const int tid = threadIdx.x;
    const int lane = tid & 63, wid = tid >> 6;
    const int quad = lane >> 4, lc = lane & 15;
    const int wm = wid >> 1, wn = wid & 1;
    const int m0 = blockIdx.y * 128, n0 = blockIdx.x * 128;
    const int l3 = lane >> 3;
    const int cs = (lane & 7) ^ l3;
    const int mloc = 2 * l3 + (cs >> 2);
    const int koff = (cs & 3) * 8;
    const int rdbase = (lc >> 1) * 64 + (((((lc & 1) << 2) | quad) ^ ((lc >> 1) & 7)) << 3);

    f32x4 acc[4][4];
#pragma unroll
    for (int mt = 0; mt < 4; ++mt)
#pragma unroll
        for (int nt = 0; nt < 4; ++nt)
            acc[mt][nt] = (f32x4){0.f, 0.f, 0.f, 0.f};

#pragma unroll
    for (int tt = 0; tt < 2; ++tt)
#pragma unroll
        for (int i = 0; i < 2; ++i) {
            int Rb = wid * 16 + i * 8;
            gl_lds16(&Ch[(size_t)(m0 + Rb * 2 + mloc) * E_ + tt * 32 + koff], &As[tt][Rb * 64]);
            gl_lds16(&Wot[(size_t)(n0 + Rb * 2 + mloc) * E_ + tt * 32 + koff], &Bs[tt][Rb * 64]);
        }

    const int NT = E_ / 32;
    for (int t = 0; t < NT; ++t) {
        const int cur = t % 3, stg = (t + 2) % 3;
        if (t + 2 < NT) {
            const int ko = (t + 2) * 32;
#pragma unroll
            for (int i = 0; i < 2; ++i) {
                int Rb = wid * 16 + i * 8;
                gl_lds16(&Ch[(size_t)(m0 + Rb * 2 + mloc) * E_ + ko + koff], &As[stg][Rb * 64]);
                gl_lds16(&Wot[(size_t)(n0 + Rb * 2 + mloc) * E_ + ko + koff], &Bs[stg][Rb * 64]);
            }
            asm volatile("s_waitcnt vmcnt(8)" ::: "memory");
        } else if (t + 1 < NT) {
            asm volatile("s_waitcnt vmcnt(4)" ::: "memory");
        } else {
            asm volatile("s_waitcnt vmcnt(0)" ::: "memory");
        }
        __builtin_amdgcn_s_barrier();
        __builtin_amdgcn_sched_barrier(0);

        short8 a[4], bfr[4];
#pragma unroll
        for (int mt = 0; mt < 4; ++mt)
            a[mt] = *(const short8*)&As[cur][(wm * 32 + mt * 8) * 64 + rdbase];
#pragma unroll
        for (int nt = 0; nt < 4; ++nt)
            bfr[nt] = *(const short8*)&Bs[cur][(wn * 32 + nt * 8) * 64 + rdbase];
#pragma unroll
        for (int mt = 0; mt < 4; ++mt)
#pragma unroll
            for (int nt = 0; nt < 4; ++nt)
                acc[mt][nt] = __builtin_amdgcn_mfma_f32_16x16x32_bf16(
                    a[mt], bfr[nt], acc[mt][nt], 0, 0, 0);

        __builtin_amdgcn_sched_barrier(0);
        __builtin_amdgcn_s_barrier();
    }

#pragma unroll
    for (int mt = 0; mt < 4; ++mt)
#pragma unroll
        for (int nt = 0; nt < 4; ++nt) {
            int n = n0 + wn * 64 + nt * 16 + lc;
            float bb = bo[n];
#pragma unroll
            for (int r = 0; r < 4; ++r) {
                int row = m0 + wm * 64 + mt * 16 + quad * 4 + r;
                out[(size_t)row * E_ + n] = acc[mt][nt][r] + bb;
            }
        }
}

// ---------------------------------------------------------------------------
extern "C" void kernel_launch(void* const* d_in, const int* in_sizes, int n_in,
                              void* d_out, int out_size, void* d_ws, size_t ws_size,
                              hipStream_t stream)
{
    const float* x  = (const float*)d_in[0];
    const float* Wq = (const float*)d_in[1];
    const float* bq = (const float*)d_in[2];
    const float* Wk = (const float*)d_in[3];
    const float* bk = (const float*)d_in[4];
    const float* Wv = (const float*)d_in[5];
    const float* bv = (const float*)d_in[6];
    const float* Wo = (const float*)d_in[7];
    const float* bo = (const float*)d_in[8];
    (void)in_sizes; (void)n_in; (void)out_size; (void)ws_size;

    const size_t N = (size_t)BH_ * S_ * D_;          // 8,388,608
    unsigned short* Wt  = (unsigned short*)d_ws;     // [3072][1024] bf16
    unsigned short* Wot = Wt + (size_t)3072 * 1024;  // [1024][1024]
    unsigned short* Xb  = Wot + (size_t)1024 * 1024; // [8192][1024]
    unsigned short* Qh  = Xb + N;                    // sliced Qg
    unsigned short* Kh  = Qh + N;                    // sliced Kg
    unsigned short* Vth = Kh + N;                    // sliced Vg
    unsigned short* Ch  = Vth + N;                   // [B,S,E]

    prep_kernel<<<dim3(8192), 256, 0, stream>>>(x, Wq, Wk, Wv, Wo, Xb, Wt, Wot);
    qkv_gemm_kernel<<<dim3(24, 64), 256, 0, stream>>>(Xb, Wt, bq, bk, bv, Qh, Kh, Vth);
    // grid.x = bh (64): all q-blocks of a bh stay on one XCD (64 % 8 == 0).
    attn_kernel<<<dim3(64, 8), 512, 0, stream>>>(Qh, Kh, Vth, Ch);
    out_proj_kernel<<<dim3(8, 64), 256, 0, stream>>>(Ch, Wot, bo, (float*)d_out);
}